// Round 1
// baseline (1012.772 us; speedup 1.0000x reference)
//
#include <hip/hip_runtime.h>

// Problem constants
#define T_  4096
#define Bb  2
#define Nn  2048
#define Cc  768
#define Ee  24
#define Dd  64
#define Hh  12

typedef __attribute__((ext_vector_type(8))) short bf16x8;
typedef __attribute__((ext_vector_type(4))) float f32x4;

__device__ __forceinline__ unsigned short f2bf(float f) {
  union { float f; unsigned int i; } u; u.f = f;
  unsigned int r = u.i + 0x7FFFu + ((u.i >> 16) & 1u);
  return (unsigned short)(r >> 16);
}
__device__ __forceinline__ float bf2f(unsigned short s) {
  union { unsigned int i; float f; } u; u.i = ((unsigned int)s) << 16; return u.f;
}

// ---------------------------------------------------------------------------
// 1. Gating: logits -> softmax -> top-12 -> gates; aux-loss atomics.
// One wave per token; block = 4 waves = 4 tokens.
// stats: [0..23] p_sum, [24..47] freqs, [48] z_sum
// ---------------------------------------------------------------------------
__global__ __launch_bounds__(256) void gate_kernel(
    const float* __restrict__ x, const float* __restrict__ wg,
    int* __restrict__ idx, float* __restrict__ gate, float* __restrict__ stats)
{
  __shared__ float xs[4][Cc];
  const int tid = threadIdx.x;
  const int t0 = blockIdx.x * 4;
  for (int i = tid; i < 4 * Cc; i += 256) xs[i / Cc][i % Cc] = x[(size_t)t0 * Cc + i];
  __syncthreads();
  const int w = tid >> 6, lane = tid & 63;
  const int t = t0 + w;

  float logit = -1e30f;
  if (lane < Ee) {
    float acc = 0.f;
    #pragma unroll 4
    for (int c = 0; c < Cc; ++c) acc += xs[w][c] * wg[c * Ee + lane];
    logit = acc;
  }
  float m = logit;
  for (int o = 32; o; o >>= 1) m = fmaxf(m, __shfl_xor(m, o));
  float p = (lane < Ee) ? expf(logit - m) : 0.f;
  float s = p;
  for (int o = 32; o; o >>= 1) s += __shfl_xor(s, o);
  float prob = p / s;
  float lse = m + logf(s);
  if (lane == 0) atomicAdd(&stats[48], lse * lse);
  if (lane < Ee) atomicAdd(&stats[lane], prob);

  // iterative top-12 (descending, ties -> lower index like lax.top_k)
  bool sel = false;
  float my_p = 0.f; int my_e = -1;
  for (int h = 0; h < Hh; ++h) {
    float v = (lane < Ee && !sel) ? prob : -1.f;
    int ix = lane;
    for (int o = 32; o; o >>= 1) {
      float ov = __shfl_xor(v, o); int oi = __shfl_xor(ix, o);
      if (ov > v || (ov == v && oi < ix)) { v = ov; ix = oi; }
    }
    if (lane == ix) sel = true;
    if (lane == h) { my_p = v; my_e = ix; }
  }
  float gsum = (lane < Hh) ? my_p : 0.f;
  for (int o = 32; o; o >>= 1) gsum += __shfl_xor(gsum, o);
  if (lane < Hh) {
    idx[t * Hh + lane] = my_e;
    gate[t * Hh + lane] = my_p / (gsum + 1e-6f);
    atomicAdd(&stats[24 + my_e], 1.0f);
  }
}

// ---------------------------------------------------------------------------
// 2. KV projection: kv = x @ W_kv + b_kv, cast to bf16.  64x64 tile, 4x4/thread.
// grid (64, 2): blockIdx.y==0 -> k cols 0..63, ==1 -> v cols 64..127
// ---------------------------------------------------------------------------
__global__ __launch_bounds__(256) void kv_kernel(
    const float* __restrict__ x, const float* __restrict__ wkv,
    const float* __restrict__ bkv, unsigned short* __restrict__ kbuf,
    unsigned short* __restrict__ vbuf)
{
  __shared__ float aT[16][68];
  __shared__ float bs[16][68];
  const int tid = threadIdx.x, r4 = tid >> 4, c4 = tid & 15;
  const int t0 = blockIdx.x * 64, cb = blockIdx.y * 64;
  float acc[4][4] = {};
  for (int k0 = 0; k0 < Cc; k0 += 16) {
    #pragma unroll
    for (int i = 0; i < 4; ++i) {
      int L = tid + i * 256;
      aT[L & 15][L >> 4] = x[(size_t)(t0 + (L >> 4)) * Cc + k0 + (L & 15)];
      bs[L >> 6][L & 63] = wkv[(k0 + (L >> 6)) * 128 + cb + (L & 63)];
    }
    __syncthreads();
    #pragma unroll
    for (int k = 0; k < 16; ++k) {
      float4 a = *(const float4*)&aT[k][r4 * 4];
      float4 b = *(const float4*)&bs[k][c4 * 4];
      float av[4] = {a.x, a.y, a.z, a.w}, bv[4] = {b.x, b.y, b.z, b.w};
      #pragma unroll
      for (int i = 0; i < 4; ++i)
        #pragma unroll
        for (int j = 0; j < 4; ++j) acc[i][j] += av[i] * bv[j];
    }
    __syncthreads();
  }
  unsigned short* dst = blockIdx.y ? vbuf : kbuf;
  #pragma unroll
  for (int i = 0; i < 4; ++i)
    #pragma unroll
    for (int j = 0; j < 4; ++j) {
      float v = acc[i][j] + bkv[cb + c4 * 4 + j];
      dst[(size_t)(t0 + r4 * 4 + i) * Dd + c4 * 4 + j] = f2bf(v);
    }
}

// ---------------------------------------------------------------------------
// 3. q_all = x @ W_in (all experts, dense) + b_in.  128x128 tile, 8x8/thread.
// grid (32, 12); cols 0..1535 map to (e = col>>6, d = col&63); b_in flat == col
// ---------------------------------------------------------------------------
__global__ __launch_bounds__(256) void qall_kernel(
    const float* __restrict__ x, const float* __restrict__ W_in,
    const float* __restrict__ b_in, float* __restrict__ qall)
{
  __shared__ float aT[16][132];
  __shared__ float bs[16][132];
  const int tid = threadIdx.x, r8 = tid >> 4, c8 = tid & 15;
  const int t0 = blockIdx.x * 128, col0 = blockIdx.y * 128;
  float acc[8][8] = {};
  for (int k0 = 0; k0 < Cc; k0 += 16) {
    #pragma unroll
    for (int i = 0; i < 8; ++i) {
      int L = tid + i * 256;                       // 2048 elems each
      aT[L & 15][L >> 4] = x[(size_t)(t0 + (L >> 4)) * Cc + k0 + (L & 15)];
      int c = L & 127, k = L >> 7;
      int gc = col0 + c;
      bs[k][c] = W_in[(size_t)(gc >> 6) * Cc * Dd + (k0 + k) * Dd + (gc & 63)];
    }
    __syncthreads();
    #pragma unroll
    for (int k = 0; k < 16; ++k) {
      float4 a0 = *(const float4*)&aT[k][r8 * 8];
      float4 a1 = *(const float4*)&aT[k][r8 * 8 + 4];
      float4 b0 = *(const float4*)&bs[k][c8 * 8];
      float4 b1 = *(const float4*)&bs[k][c8 * 8 + 4];
      float av[8] = {a0.x, a0.y, a0.z, a0.w, a1.x, a1.y, a1.z, a1.w};
      float bv[8] = {b0.x, b0.y, b0.z, b0.w, b1.x, b1.y, b1.z, b1.w};
      #pragma unroll
      for (int i = 0; i < 8; ++i)
        #pragma unroll
        for (int j = 0; j < 8; ++j) acc[i][j] += av[i] * bv[j];
    }
    __syncthreads();
  }
  #pragma unroll
  for (int i = 0; i < 8; ++i) {
    size_t t = t0 + r8 * 8 + i;
    int cbase = col0 + c8 * 8;
    float4 o0, o1;
    o0.x = acc[i][0] + b_in[cbase + 0]; o0.y = acc[i][1] + b_in[cbase + 1];
    o0.z = acc[i][2] + b_in[cbase + 2]; o0.w = acc[i][3] + b_in[cbase + 3];
    o1.x = acc[i][4] + b_in[cbase + 4]; o1.y = acc[i][5] + b_in[cbase + 5];
    o1.z = acc[i][6] + b_in[cbase + 6]; o1.w = acc[i][7] + b_in[cbase + 7];
    *(float4*)&qall[t * (Ee * Dd) + cbase] = o0;
    *(float4*)&qall[t * (Ee * Dd) + cbase + 4] = o1;
  }
}

// ---------------------------------------------------------------------------
// 4. Gather selected q (f32 -> bf16) into [B,H,N,D]
// ---------------------------------------------------------------------------
__global__ __launch_bounds__(256) void gatherq_kernel(
    const float* __restrict__ qall, const int* __restrict__ idx,
    unsigned short* __restrict__ qh)
{
  const int t = blockIdx.x, b = t >> 11, nn = t & (Nn - 1);
  for (int i = threadIdx.x; i < Hh * Dd; i += 256) {
    int h = i >> 6, d = i & 63;
    int e = idx[t * Hh + h];
    qh[((size_t)(b * Hh + h) * Nn + nn) * Dd + d] =
        f2bf(qall[(size_t)t * (Ee * Dd) + e * Dd + d]);
  }
}

// ---------------------------------------------------------------------------
// 5. Flash attention, MFMA 16x16x32 bf16.  Block = 4 waves, 64 queries;
// wave owns 16 queries.  Key tile = 64.  Grid (N/64, B*H).
// A-frag: A[m=lane&15][k=quad*8+j]; B-frag: B[k=quad*8+j][n=lane&15];
// C/D: col=lane&15, row=quad*4+reg.
// ---------------------------------------------------------------------------
#define PADK 72
__global__ __launch_bounds__(256) void attn_kernel(
    const unsigned short* __restrict__ qh, const unsigned short* __restrict__ kbuf,
    const unsigned short* __restrict__ vbuf, float* __restrict__ obuf)
{
  __shared__ __align__(16) unsigned short ks[64 * PADK];   // [key][d]
  __shared__ __align__(16) unsigned short vT[64 * PADK];   // [d][key]
  __shared__ __align__(16) unsigned short pl[4 * 16 * PADK]; // per-wave P [q][key]

  const int tid = threadIdx.x;
  const int w = tid >> 6, lane = tid & 63;
  const int quad = lane >> 4, nl = lane & 15;
  const int bh = blockIdx.y;
  const int b = bh / Hh;
  const int i0 = blockIdx.x * 64;

  const unsigned short* qrow = qh + ((size_t)(bh * Nn + i0 + w * 16 + nl)) * Dd;
  bf16x8 qA0 = *(const bf16x8*)(qrow + quad * 8);
  bf16x8 qA1 = *(const bf16x8*)(qrow + 32 + quad * 8);

  f32x4 acc[4];
  #pragma unroll
  for (int f = 0; f < 4; ++f) acc[f] = (f32x4){0.f, 0.f, 0.f, 0.f};
  float m_r[4] = {-1e30f, -1e30f, -1e30f, -1e30f};
  float l_r[4] = {0.f, 0.f, 0.f, 0.f};
  unsigned short* plw = pl + w * 16 * PADK;

  for (int j0 = 0; j0 < Nn; j0 += 64) {
    const unsigned short* kb = kbuf + ((size_t)(b * Nn + j0)) * Dd;
    const unsigned short* vb = vbuf + ((size_t)(b * Nn + j0)) * Dd;
    #pragma unroll
    for (int it = 0; it < 16; ++it) {
      int L = tid + it * 256;
      int key = L >> 6, d = L & 63;
      ks[key * PADK + d] = kb[key * Dd + d];
      vT[d * PADK + key] = vb[key * Dd + d];
    }
    __syncthreads();

    f32x4 sv[4];
    #pragma unroll
    for (int kg = 0; kg < 4; ++kg) {
      const unsigned short* kr = ks + (kg * 16 + nl) * PADK;
      bf16x8 b0 = *(const bf16x8*)(kr + quad * 8);
      bf16x8 b1 = *(const bf16x8*)(kr + 32 + quad * 8);
      f32x4 c = {0.f, 0.f, 0.f, 0.f};
      c = __builtin_amdgcn_mfma_f32_16x16x32_bf16(qA0, b0, c, 0, 0, 0);
      c = __builtin_amdgcn_mfma_f32_16x16x32_bf16(qA1, b1, c, 0, 0, 0);
      sv[kg] = c;
    }

    #pragma unroll
    for (int reg = 0; reg < 4; ++reg) {
      float s[4];
      #pragma unroll
      for (int kg = 0; kg < 4; ++kg) s[kg] = sv[kg][reg] * 0.125f;
      float loc = fmaxf(fmaxf(s[0], s[1]), fmaxf(s[2], s[3]));
      loc = fmaxf(loc, __shfl_xor(loc, 1));
      loc = fmaxf(loc, __shfl_xor(loc, 2));
      loc = fmaxf(loc, __shfl_xor(loc, 4));
      loc = fmaxf(loc, __shfl_xor(loc, 8));
      float mx = fmaxf(m_r[reg], loc);
      float alpha = __expf(m_r[reg] - mx);
      m_r[reg] = mx;
      float ls = 0.f;
      unsigned short us[4];
      #pragma unroll
      for (int kg = 0; kg < 4; ++kg) {
        float p = __expf(s[kg] - mx);
        us[kg] = f2bf(p);
        ls += bf2f(us[kg]);          // normalize with the rounded P we actually use
      }
      ls += __shfl_xor(ls, 1);
      ls += __shfl_xor(ls, 2);
      ls += __shfl_xor(ls, 4);
      ls += __shfl_xor(ls, 8);
      l_r[reg] = l_r[reg] * alpha + ls;
      #pragma unroll
      for (int f = 0; f < 4; ++f) acc[f][reg] *= alpha;
      unsigned short* pr = plw + (quad * 4 + reg) * PADK + nl;
      pr[0] = us[0]; pr[16] = us[1]; pr[32] = us[2]; pr[48] = us[3];
    }
    // P writes/reads are wave-internal (per-wave region) -> in-order DS pipe ok
    bf16x8 pA0 = *(const bf16x8*)(plw + nl * PADK + quad * 8);
    bf16x8 pA1 = *(const bf16x8*)(plw + nl * PADK + 32 + quad * 8);
    #pragma unroll
    for (int f = 0; f < 4; ++f) {
      const unsigned short* vr = vT + (f * 16 + nl) * PADK;
      bf16x8 v0 = *(const bf16x8*)(vr + quad * 8);
      bf16x8 v1 = *(const bf16x8*)(vr + 32 + quad * 8);
      acc[f] = __builtin_amdgcn_mfma_f32_16x16x32_bf16(pA0, v0, acc[f], 0, 0, 0);
      acc[f] = __builtin_amdgcn_mfma_f32_16x16x32_bf16(pA1, v1, acc[f], 0, 0, 0);
    }
    __syncthreads();
  }

  float* orow = obuf + ((size_t)(bh * Nn + i0 + w * 16)) * Dd;
  #pragma unroll
  for (int f = 0; f < 4; ++f)
    #pragma unroll
    for (int reg = 0; reg < 4; ++reg)
      orow[(quad * 4 + reg) * Dd + f * 16 + nl] = acc[f][reg] / l_r[reg];
}

// ---------------------------------------------------------------------------
// 6. Scatter gated o into dense xeg[T][1560]: cols 0..1535 = g*o at expert slot,
// cols 1536..1559 = dense gates (for the b_out term).  xeg pre-zeroed.
// ---------------------------------------------------------------------------
__global__ __launch_bounds__(256) void scatter_kernel(
    const float* __restrict__ obuf, const int* __restrict__ idx,
    const float* __restrict__ gate, float* __restrict__ xeg)
{
  const int t = blockIdx.x, b = t >> 11, nn = t & (Nn - 1);
  for (int i = threadIdx.x; i < Hh * Dd; i += 256) {
    int h = i >> 6, d = i & 63;
    int e = idx[t * Hh + h];
    float g = gate[t * Hh + h];
    xeg[(size_t)t * 1560 + e * Dd + d] =
        g * obuf[((size_t)(b * Hh + h) * Nn + nn) * Dd + d];
  }
  if (threadIdx.x < Hh) {
    int e = idx[t * Hh + threadIdx.x];
    xeg[(size_t)t * 1560 + 1536 + e] = gate[t * Hh + threadIdx.x];
  }
}

// ---------------------------------------------------------------------------
// 7. out = xeg @ [W_out ; b_out]   ([4096x1560]@[1560x768]).  128x128 tile.
// W_out flat [E,D,C] is exactly row-major [1536][768].  grid (32, 6)
// ---------------------------------------------------------------------------
__global__ __launch_bounds__(256) void reduce_kernel(
    const float* __restrict__ xeg, const float* __restrict__ wout,
    const float* __restrict__ bout, float* __restrict__ out)
{
  __shared__ float aT[24][132];
  __shared__ float bs[24][132];
  const int tid = threadIdx.x, r8 = tid >> 4, c8 = tid & 15;
  const int t0 = blockIdx.x * 128, c0 = blockIdx.y * 128;
  float acc[8][8] = {};
  for (int k0 = 0; k0 < 1560; k0 += 24) {
    #pragma unroll
    for (int i = 0; i < 12; ++i) {                 // 3072 A elems
      int L = tid + i * 256;
      int k = L % 24, tl = L / 24;
      aT[k][tl] = xeg[(size_t)(t0 + tl) * 1560 + k0 + k];
      int c = L & 127, kb = L >> 7;                // 3072 B elems (kb 0..23)
      int kk = k0 + kb;
      bs[kb][c] = (kk < 1536) ? wout[(size_t)kk * Cc + c0 + c]
                              : bout[(size_t)(kk - 1536) * Cc + c0 + c];
    }
    __syncthreads();
    #pragma unroll
    for (int k = 0; k < 24; ++k) {
      float4 a0 = *(const float4*)&aT[k][r8 * 8];
      float4 a1 = *(const float4*)&aT[k][r8 * 8 + 4];
      float4 b0 = *(const float4*)&bs[k][c8 * 8];
      float4 b1 = *(const float4*)&bs[k][c8 * 8 + 4];
      float av[8] = {a0.x, a0.y, a0.z, a0.w, a1.x, a1.y, a1.z, a1.w};
      float bv[8] = {b0.x, b0.y, b0.z, b0.w, b1.x, b1.y, b1.z, b1.w};
      #pragma unroll
      for (int i = 0; i < 8; ++i)
        #pragma unroll
        for (int j = 0; j < 8; ++j) acc[i][j] += av[i] * bv[j];
    }
    __syncthreads();
  }
  #pragma unroll
  for (int i = 0; i < 8; ++i) {
    size_t t = t0 + r8 * 8 + i;
    int cb = c0 + c8 * 8;
    float4 o0 = {acc[i][0], acc[i][1], acc[i][2], acc[i][3]};
    float4 o1 = {acc[i][4], acc[i][5], acc[i][6], acc[i][7]};
    *(float4*)&out[t * Cc + cb] = o0;
    *(float4*)&out[t * Cc + cb + 4] = o1;
  }
}

// ---------------------------------------------------------------------------
// 8. Aux loss finalize
// ---------------------------------------------------------------------------
__global__ void aux_kernel(const float* __restrict__ stats,
                           float* __restrict__ out, int out_size)
{
  if (threadIdx.x == 0 && blockIdx.x == 0) {
    float pt = 0.f, ft = 0.f, sw = 0.f;
    for (int e = 0; e < Ee; ++e) { pt += stats[e]; ft += stats[24 + e]; }
    for (int e = 0; e < Ee; ++e) sw += stats[e] * stats[24 + e];
    float sswitch = (float)Ee * sw / (pt * ft);
    float z = stats[48] * (1.0f / (float)T_);
    out[out_size - 1] = 0.1f * sswitch + 0.001f * z;
  }
}

// ---------------------------------------------------------------------------
extern "C" void kernel_launch(void* const* d_in, const int* in_sizes, int n_in,
                              void* d_out, int out_size, void* d_ws, size_t ws_size,
                              hipStream_t stream)
{
  const float* x     = (const float*)d_in[0];
  const float* wg    = (const float*)d_in[1];
  const float* W_in  = (const float*)d_in[2];
  const float* b_in  = (const float*)d_in[3];
  const float* W_out = (const float*)d_in[4];
  const float* b_out = (const float*)d_in[5];
  const float* W_kv  = (const float*)d_in[6];
  const float* b_kv  = (const float*)d_in[7];
  float* out = (float*)d_out;

  // workspace carve-up (~79 MB total)
  char* ws = (char*)d_ws;
  size_t off = 0;
  auto carve = [&](size_t bytes) -> void* {
    void* p = ws + off;
    off = (off + bytes + 255) & ~(size_t)255;
    return p;
  };
  int*            idx   = (int*)           carve((size_t)T_ * Hh * 4);
  float*          gate  = (float*)         carve((size_t)T_ * Hh * 4);
  float*          stats = (float*)         carve(256);
  unsigned short* kbuf  = (unsigned short*)carve((size_t)T_ * Dd * 2);
  unsigned short* vbuf  = (unsigned short*)carve((size_t)T_ * Dd * 2);
  float*          qall  = (float*)         carve((size_t)T_ * Ee * Dd * 4);
  unsigned short* qh    = (unsigned short*)carve((size_t)T_ * Hh * Dd * 2);
  float*          obuf  = (float*)         carve((size_t)T_ * Hh * Dd * 4);
  float*          xeg   = (float*)         carve((size_t)T_ * 1560 * 4);

  hipMemsetAsync(stats, 0, 256, stream);
  hipMemsetAsync(xeg, 0, (size_t)T_ * 1560 * 4, stream);

  gate_kernel<<<T_ / 4, 256, 0, stream>>>(x, wg, idx, gate, stats);
  kv_kernel<<<dim3(T_ / 64, 2), 256, 0, stream>>>(x, W_kv, b_kv, kbuf, vbuf);
  qall_kernel<<<dim3(T_ / 128, (Ee * Dd) / 128), 256, 0, stream>>>(x, W_in, b_in, qall);
  gatherq_kernel<<<T_, 256, 0, stream>>>(qall, idx, qh);
  attn_kernel<<<dim3(Nn / 64, Bb * Hh), 256, 0, stream>>>(qh, kbuf, vbuf, obuf);
  scatter_kernel<<<T_, 256, 0, stream>>>(obuf, idx, gate, xeg);
  reduce_kernel<<<dim3(T_ / 128, Cc / 128), 256, 0, stream>>>(xeg, W_out, b_out, out);
  aux_kernel<<<1, 64, 0, stream>>>(stats, out, out_size);
}

// Round 2
// 497.816 us; speedup vs baseline: 2.0344x; 2.0344x over previous
//
#include <hip/hip_runtime.h>

// Problem constants
#define T_  4096
#define Bb  2
#define Nn  2048
#define Cc  768
#define Ee  24
#define Dd  64
#define Hh  12
#define KR  1568   // reduce GEMM K: 1536 (W_out) + 24 (b_out via dense gates) + 8 pad

typedef __attribute__((ext_vector_type(8))) short bf16x8;
typedef __attribute__((ext_vector_type(4))) float f32x4;

__device__ __forceinline__ unsigned short f2bf(float f) {
  union { float f; unsigned int i; } u; u.f = f;
  unsigned int r = u.i + 0x7FFFu + ((u.i >> 16) & 1u);
  return (unsigned short)(r >> 16);
}
__device__ __forceinline__ float bf2f(unsigned short s) {
  union { unsigned int i; float f; } u; u.i = ((unsigned int)s) << 16; return u.f;
}

__device__ __forceinline__ void gload16(const void* g, void* l) {
  __builtin_amdgcn_global_load_lds(
      (const __attribute__((address_space(1))) void*)g,
      (__attribute__((address_space(3))) void*)l, 16, 0, 0);
}

// ---------------------------------------------------------------------------
// Conversion kernels (weights -> bf16 B^T layouts, x -> bf16)
// ---------------------------------------------------------------------------
__global__ __launch_bounds__(256) void convert_x_kernel(
    const float* __restrict__ x, unsigned short* __restrict__ xb)
{
  int i = blockIdx.x * 256 + threadIdx.x;          // one float4 each
  float4 v = ((const float4*)x)[i];
  ushort4 o;
  o.x = f2bf(v.x); o.y = f2bf(v.y); o.z = f2bf(v.z); o.w = f2bf(v.w);
  ((ushort4*)xb)[i] = o;
}

// W_in [E][C][D] -> BqT [E*D][C] bf16  (per-expert transpose)
__global__ __launch_bounds__(256) void convert_win_kernel(
    const float* __restrict__ W_in, unsigned short* __restrict__ BqT)
{
  __shared__ float ls[64][65];
  const int e = blockIdx.x, c0 = blockIdx.y * 64, tid = threadIdx.x;
  #pragma unroll
  for (int i = 0; i < 16; ++i) {
    int L = tid + i * 256, c = L >> 6, d = L & 63;
    ls[c][d] = W_in[(size_t)e * Cc * Dd + (size_t)(c0 + c) * Dd + d];
  }
  __syncthreads();
  #pragma unroll
  for (int i = 0; i < 16; ++i) {
    int L = tid + i * 256, d = L >> 6, c = L & 63;
    BqT[(size_t)(e * Dd + d) * Cc + c0 + c] = f2bf(ls[c][d]);
  }
}

// [W_out ; b_out ; 0] -> BrT [768][KR] bf16
__global__ __launch_bounds__(256) void convert_wout_kernel(
    const float* __restrict__ W_out, const float* __restrict__ b_out,
    unsigned short* __restrict__ BrT)
{
  __shared__ float ls[32][65];
  const int k0 = blockIdx.x * 32, n0 = blockIdx.y * 64, tid = threadIdx.x;
  #pragma unroll
  for (int i = 0; i < 8; ++i) {
    int L = tid + i * 256, k = L >> 6, n = L & 63;
    int kk = k0 + k;
    float v = (kk < 1536) ? W_out[(size_t)kk * Cc + n0 + n]
            : (kk < 1560) ? b_out[(size_t)(kk - 1536) * Cc + n0 + n] : 0.f;
    ls[k][n] = v;
  }
  __syncthreads();
  #pragma unroll
  for (int i = 0; i < 8; ++i) {
    int L = tid + i * 256, n = L >> 5, k = L & 31;
    BrT[(size_t)(n0 + n) * KR + k0 + k] = f2bf(ls[k][n]);
  }
}

// W_kv [C][128] -> BkvT [128][C] bf16
__global__ __launch_bounds__(256) void convert_wkv_kernel(
    const float* __restrict__ W_kv, unsigned short* __restrict__ BkvT)
{
  __shared__ float ls[64][129];
  const int c0 = blockIdx.x * 64, tid = threadIdx.x;
  #pragma unroll
  for (int i = 0; i < 32; ++i) {
    int L = tid + i * 256, c = L >> 7, j = L & 127;
    ls[c][j] = W_kv[(size_t)(c0 + c) * 128 + j];
  }
  __syncthreads();
  #pragma unroll
  for (int i = 0; i < 32; ++i) {
    int L = tid + i * 256, j = L >> 6, c = L & 63;
    BkvT[(size_t)j * Cc + c0 + c] = f2bf(ls[c][j]);
  }
}

// ---------------------------------------------------------------------------
// bf16 MFMA GEMM (m97 structure): C[M][N] = A[M][K]bf16 @ BT[N][K]bf16^T (+bias)
// 128x128 tile, BK=32, 4 waves each 64x64, global_load_lds width-16 staging.
// grid (M/128, N/128)
// ---------------------------------------------------------------------------
template<bool BF16OUT, bool HASBIAS>
__global__ __launch_bounds__(256) void gemm_bt_kernel(
    const unsigned short* __restrict__ A, const unsigned short* __restrict__ BT,
    const float* __restrict__ bias, void* __restrict__ Cout, int K, int ldc)
{
  __shared__ __align__(16) unsigned short As[128 * 32];
  __shared__ __align__(16) unsigned short Bs[128 * 32];
  const int tid = threadIdx.x, w = tid >> 6, lane = tid & 63;
  const int quad = lane >> 4, nl = lane & 15;
  const int m0 = blockIdx.x * 128, n0 = blockIdx.y * 128;
  const int mw = (w & 1) * 64, nw = (w >> 1) * 64;

  f32x4 acc[4][4];
  #pragma unroll
  for (int i = 0; i < 4; ++i)
    #pragma unroll
    for (int j = 0; j < 4; ++j) acc[i][j] = (f32x4){0.f, 0.f, 0.f, 0.f};

  // staging: wave w loads tile rows w*32 .. w*32+31 (2 instrs of 16 rows each)
  const int row0 = w * 32 + (lane >> 2);
  const int col8 = (lane & 3) * 8;                      // element offset (16B)
  const unsigned short* a0 = A + (size_t)(m0 + row0) * K + col8;
  const unsigned short* a1 = a0 + (size_t)16 * K;
  const unsigned short* b0 = BT + (size_t)(n0 + row0) * K + col8;
  const unsigned short* b1 = b0 + (size_t)16 * K;
  unsigned short* lA0 = As + (w * 32) * 32;
  unsigned short* lA1 = As + (w * 32 + 16) * 32;
  unsigned short* lB0 = Bs + (w * 32) * 32;
  unsigned short* lB1 = Bs + (w * 32 + 16) * 32;

  for (int k0 = 0; k0 < K; k0 += 32) {
    gload16(a0 + k0, lA0);
    gload16(a1 + k0, lA1);
    gload16(b0 + k0, lB0);
    gload16(b1 + k0, lB1);
    __syncthreads();                       // drains vmcnt (staging complete)

    bf16x8 af[4], bfr[4];
    #pragma unroll
    for (int mi = 0; mi < 4; ++mi)
      af[mi] = *(const bf16x8*)&As[(mw + mi * 16 + nl) * 32 + quad * 8];
    #pragma unroll
    for (int ni = 0; ni < 4; ++ni)
      bfr[ni] = *(const bf16x8*)&Bs[(nw + ni * 16 + nl) * 32 + quad * 8];
    #pragma unroll
    for (int mi = 0; mi < 4; ++mi)
      #pragma unroll
      for (int ni = 0; ni < 4; ++ni)
        acc[mi][ni] = __builtin_amdgcn_mfma_f32_16x16x32_bf16(
            af[mi], bfr[ni], acc[mi][ni], 0, 0, 0);
    __syncthreads();                       // fragments consumed; safe to restage
  }

  #pragma unroll
  for (int mi = 0; mi < 4; ++mi) {
    int rowb = m0 + mw + mi * 16 + quad * 4;
    #pragma unroll
    for (int ni = 0; ni < 4; ++ni) {
      int col = n0 + nw + ni * 16 + nl;
      float bv = HASBIAS ? bias[col] : 0.f;
      #pragma unroll
      for (int reg = 0; reg < 4; ++reg) {
        float v = acc[mi][ni][reg] + bv;
        if (BF16OUT)
          ((unsigned short*)Cout)[(size_t)(rowb + reg) * ldc + col] = f2bf(v);
        else
          ((float*)Cout)[(size_t)(rowb + reg) * ldc + col] = v;
      }
    }
  }
}

// ---------------------------------------------------------------------------
// Gating: one wave per token. stats: [0..23] p_sum, [24..47] freqs, [48] z_sum
// ---------------------------------------------------------------------------
__global__ __launch_bounds__(256) void gate_kernel(
    const float* __restrict__ x, const float* __restrict__ wg,
    int* __restrict__ idx, float* __restrict__ gate, float* __restrict__ stats)
{
  __shared__ float xs[4][Cc];
  const int tid = threadIdx.x;
  const int t0 = blockIdx.x * 4;
  for (int i = tid; i < 4 * Cc; i += 256) xs[i / Cc][i % Cc] = x[(size_t)t0 * Cc + i];
  __syncthreads();
  const int w = tid >> 6, lane = tid & 63;
  const int t = t0 + w;

  float logit = -1e30f;
  if (lane < Ee) {
    float acc = 0.f;
    #pragma unroll 4
    for (int c = 0; c < Cc; ++c) acc += xs[w][c] * wg[c * Ee + lane];
    logit = acc;
  }
  float m = logit;
  for (int o = 32; o; o >>= 1) m = fmaxf(m, __shfl_xor(m, o));
  float p = (lane < Ee) ? expf(logit - m) : 0.f;
  float s = p;
  for (int o = 32; o; o >>= 1) s += __shfl_xor(s, o);
  float prob = p / s;
  float lse = m + logf(s);
  if (lane == 0) atomicAdd(&stats[48], lse * lse);
  if (lane < Ee) atomicAdd(&stats[lane], prob);

  bool sel = false;
  float my_p = 0.f; int my_e = -1;
  for (int h = 0; h < Hh; ++h) {
    float v = (lane < Ee && !sel) ? prob : -1.f;
    int ix = lane;
    for (int o = 32; o; o >>= 1) {
      float ov = __shfl_xor(v, o); int oi = __shfl_xor(ix, o);
      if (ov > v || (ov == v && oi < ix)) { v = ov; ix = oi; }
    }
    if (lane == ix) sel = true;
    if (lane == h) { my_p = v; my_e = ix; }
  }
  float gsum = (lane < Hh) ? my_p : 0.f;
  for (int o = 32; o; o >>= 1) gsum += __shfl_xor(gsum, o);
  if (lane < Hh) {
    idx[t * Hh + lane] = my_e;
    gate[t * Hh + lane] = my_p / (gsum + 1e-6f);
    atomicAdd(&stats[24 + my_e], 1.0f);
  }
}

// ---------------------------------------------------------------------------
// Gather selected q (bf16 -> bf16) into [B,H,N,D]
// ---------------------------------------------------------------------------
__global__ __launch_bounds__(256) void gatherq_kernel(
    const unsigned short* __restrict__ qallb, const int* __restrict__ idx,
    unsigned short* __restrict__ qh)
{
  const int t = blockIdx.x, b = t >> 11, nn = t & (Nn - 1);
  for (int i = threadIdx.x; i < Hh * Dd; i += 256) {
    int h = i >> 6, d = i & 63;
    int e = idx[t * Hh + h];
    qh[((size_t)(b * Hh + h) * Nn + nn) * Dd + d] =
        qallb[(size_t)t * (Ee * Dd) + e * Dd + d];
  }
}

// ---------------------------------------------------------------------------
// Flash attention, MFMA 16x16x32 bf16.  kvbuf packed [T][128]: k 0..63, v 64..127
// ---------------------------------------------------------------------------
#define PADK 72
__global__ __launch_bounds__(256) void attn_kernel(
    const unsigned short* __restrict__ qh, const unsigned short* __restrict__ kvbuf,
    float* __restrict__ obuf)
{
  __shared__ __align__(16) unsigned short ks[64 * PADK];   // [key][d]
  __shared__ __align__(16) unsigned short vT[64 * PADK];   // [d][key]
  __shared__ __align__(16) unsigned short pl[4 * 16 * PADK]; // per-wave P [q][key]

  const int tid = threadIdx.x;
  const int w = tid >> 6, lane = tid & 63;
  const int quad = lane >> 4, nl = lane & 15;
  const int bh = blockIdx.y;
  const int b = bh / Hh;
  const int i0 = blockIdx.x * 64;

  const unsigned short* qrow = qh + ((size_t)(bh * Nn + i0 + w * 16 + nl)) * Dd;
  bf16x8 qA0 = *(const bf16x8*)(qrow + quad * 8);
  bf16x8 qA1 = *(const bf16x8*)(qrow + 32 + quad * 8);

  f32x4 acc[4];
  #pragma unroll
  for (int f = 0; f < 4; ++f) acc[f] = (f32x4){0.f, 0.f, 0.f, 0.f};
  float m_r[4] = {-1e30f, -1e30f, -1e30f, -1e30f};
  float l_r[4] = {0.f, 0.f, 0.f, 0.f};
  unsigned short* plw = pl + w * 16 * PADK;

  for (int j0 = 0; j0 < Nn; j0 += 64) {
    const unsigned short* kb = kvbuf + ((size_t)(b * Nn + j0)) * 128;
    #pragma unroll
    for (int it = 0; it < 16; ++it) {
      int L = tid + it * 256;
      int key = L >> 6, d = L & 63;
      ks[key * PADK + d] = kb[key * 128 + d];
      vT[d * PADK + key] = kb[key * 128 + 64 + d];
    }
    __syncthreads();

    f32x4 sv[4];
    #pragma unroll
    for (int kg = 0; kg < 4; ++kg) {
      const unsigned short* kr = ks + (kg * 16 + nl) * PADK;
      bf16x8 b0 = *(const bf16x8*)(kr + quad * 8);
      bf16x8 b1 = *(const bf16x8*)(kr + 32 + quad * 8);
      f32x4 c = {0.f, 0.f, 0.f, 0.f};
      c = __builtin_amdgcn_mfma_f32_16x16x32_bf16(qA0, b0, c, 0, 0, 0);
      c = __builtin_amdgcn_mfma_f32_16x16x32_bf16(qA1, b1, c, 0, 0, 0);
      sv[kg] = c;
    }

    #pragma unroll
    for (int reg = 0; reg < 4; ++reg) {
      float s[4];
      #pragma unroll
      for (int kg = 0; kg < 4; ++kg) s[kg] = sv[kg][reg] * 0.125f;
      float loc = fmaxf(fmaxf(s[0], s[1]), fmaxf(s[2], s[3]));
      loc = fmaxf(loc, __shfl_xor(loc, 1));
      loc = fmaxf(loc, __shfl_xor(loc, 2));
      loc = fmaxf(loc, __shfl_xor(loc, 4));
      loc = fmaxf(loc, __shfl_xor(loc, 8));
      float mx = fmaxf(m_r[reg], loc);
      float alpha = __expf(m_r[reg] - mx);
      m_r[reg] = mx;
      float ls = 0.f;
      unsigned short us[4];
      #pragma unroll
      for (int kg = 0; kg < 4; ++kg) {
        float p = __expf(s[kg] - mx);
        us[kg] = f2bf(p);
        ls += bf2f(us[kg]);
      }
      ls += __shfl_xor(ls, 1);
      ls += __shfl_xor(ls, 2);
      ls += __shfl_xor(ls, 4);
      ls += __shfl_xor(ls, 8);
      l_r[reg] = l_r[reg] * alpha + ls;
      #pragma unroll
      for (int f = 0; f < 4; ++f) acc[f][reg] *= alpha;
      unsigned short* pr = plw + (quad * 4 + reg) * PADK + nl;
      pr[0] = us[0]; pr[16] = us[1]; pr[32] = us[2]; pr[48] = us[3];
    }
    bf16x8 pA0 = *(const bf16x8*)(plw + nl * PADK + quad * 8);
    bf16x8 pA1 = *(const bf16x8*)(plw + nl * PADK + 32 + quad * 8);
    #pragma unroll
    for (int f = 0; f < 4; ++f) {
      const unsigned short* vr = vT + (f * 16 + nl) * PADK;
      bf16x8 v0 = *(const bf16x8*)(vr + quad * 8);
      bf16x8 v1 = *(const bf16x8*)(vr + 32 + quad * 8);
      acc[f] = __builtin_amdgcn_mfma_f32_16x16x32_bf16(pA0, v0, acc[f], 0, 0, 0);
      acc[f] = __builtin_amdgcn_mfma_f32_16x16x32_bf16(pA1, v1, acc[f], 0, 0, 0);
    }
    __syncthreads();
  }

  float* orow = obuf + ((size_t)(bh * Nn + i0 + w * 16)) * Dd;
  #pragma unroll
  for (int f = 0; f < 4; ++f)
    #pragma unroll
    for (int reg = 0; reg < 4; ++reg)
      orow[(quad * 4 + reg) * Dd + f * 16 + nl] = acc[f][reg] / l_r[reg];
}

// ---------------------------------------------------------------------------
// Scatter gated o into dense bf16 xeg[T][KR]: cols e*64+d = g*o,
// cols 1536+e = dense gates (b_out K-rows), 1560..1567 zero. xeg pre-zeroed.
// ---------------------------------------------------------------------------
__global__ __launch_bounds__(256) void scatter_kernel(
    const float* __restrict__ obuf, const int* __restrict__ idx,
    const float* __restrict__ gate, unsigned short* __restrict__ xeg)
{
  const int t = blockIdx.x, b = t >> 11, nn = t & (Nn - 1);
  for (int i = threadIdx.x; i < Hh * Dd; i += 256) {
    int h = i >> 6, d = i & 63;
    int e = idx[t * Hh + h];
    float g = gate[t * Hh + h];
    xeg[(size_t)t * KR + e * Dd + d] =
        f2bf(g * obuf[((size_t)(b * Hh + h) * Nn + nn) * Dd + d]);
  }
  if (threadIdx.x < Hh) {
    int e = idx[t * Hh + threadIdx.x];
    xeg[(size_t)t * KR + 1536 + e] = f2bf(gate[t * Hh + threadIdx.x]);
  }
}

// ---------------------------------------------------------------------------
// Aux loss finalize
// ---------------------------------------------------------------------------
__global__ void aux_kernel(const float* __restrict__ stats,
                           float* __restrict__ out, int out_size)
{
  if (threadIdx.x == 0 && blockIdx.x == 0) {
    float pt = 0.f, ft = 0.f, sw = 0.f;
    for (int e = 0; e < Ee; ++e) { pt += stats[e]; ft += stats[24 + e]; }
    for (int e = 0; e < Ee; ++e) sw += stats[e] * stats[24 + e];
    float sswitch = (float)Ee * sw / (pt * ft);
    float z = stats[48] * (1.0f / (float)T_);
    out[out_size - 1] = 0.1f * sswitch + 0.001f * z;
  }
}

// ---------------------------------------------------------------------------
extern "C" void kernel_launch(void* const* d_in, const int* in_sizes, int n_in,
                              void* d_out, int out_size, void* d_ws, size_t ws_size,
                              hipStream_t stream)
{
  const float* x     = (const float*)d_in[0];
  const float* wg    = (const float*)d_in[1];
  const float* W_in  = (const float*)d_in[2];
  const float* b_in  = (const float*)d_in[3];
  const float* W_out = (const float*)d_in[4];
  const float* b_out = (const float*)d_in[5];
  const float* W_kv  = (const float*)d_in[6];
  const float* b_kv  = (const float*)d_in[7];
  float* out = (float*)d_out;

  char* ws = (char*)d_ws;
  size_t off = 0;
  auto carve = [&](size_t bytes) -> void* {
    void* p = ws + off;
    off = (off + bytes + 255) & ~(size_t)255;
    return p;
  };
  int*            idx   = (int*)           carve((size_t)T_ * Hh * 4);
  float*          gate  = (float*)         carve((size_t)T_ * Hh * 4);
  float*          stats = (float*)         carve(256);
  unsigned short* xb    = (unsigned short*)carve((size_t)T_ * Cc * 2);
  unsigned short* BqT   = (unsigned short*)carve((size_t)Ee * Dd * Cc * 2);
  unsigned short* BrT   = (unsigned short*)carve((size_t)Cc * KR * 2);
  unsigned short* BkvT  = (unsigned short*)carve((size_t)128 * Cc * 2);
  unsigned short* kvbuf = (unsigned short*)carve((size_t)T_ * 128 * 2);
  unsigned short* qallb = (unsigned short*)carve((size_t)T_ * Ee * Dd * 2);
  unsigned short* qh    = (unsigned short*)carve((size_t)T_ * Hh * Dd * 2);
  float*          obuf  = (float*)         carve((size_t)T_ * Hh * Dd * 4);
  unsigned short* xeg   = (unsigned short*)carve((size_t)T_ * KR * 2);

  hipMemsetAsync(stats, 0, 256, stream);
  hipMemsetAsync(xeg, 0, (size_t)T_ * KR * 2, stream);

  // conversions
  convert_x_kernel  <<<T_ * Cc / 4 / 256, 256, 0, stream>>>(x, xb);
  convert_win_kernel<<<dim3(Ee, Cc / 64), 256, 0, stream>>>(W_in, BqT);
  convert_wout_kernel<<<dim3(KR / 32, Cc / 64), 256, 0, stream>>>(W_out, b_out, BrT);
  convert_wkv_kernel<<<Cc / 64, 256, 0, stream>>>(W_kv, BkvT);

  gate_kernel<<<T_ / 4, 256, 0, stream>>>(x, wg, idx, gate, stats);

  // kv = xb @ BkvT^T + b_kv  -> bf16 [T][128]
  gemm_bt_kernel<true, true><<<dim3(T_ / 128, 1), 256, 0, stream>>>(
      xb, BkvT, b_kv, kvbuf, Cc, 128);
  // q_all = xb @ BqT^T + b_in -> bf16 [T][1536]
  gemm_bt_kernel<true, true><<<dim3(T_ / 128, Ee * Dd / 128), 256, 0, stream>>>(
      xb, BqT, b_in, qallb, Cc, Ee * Dd);

  gatherq_kernel<<<T_, 256, 0, stream>>>(qallb, idx, qh);
  attn_kernel<<<dim3(Nn / 64, Bb * Hh), 256, 0, stream>>>(qh, kvbuf, obuf);
  scatter_kernel<<<T_, 256, 0, stream>>>(obuf, idx, gate, xeg);

  // out = xeg @ BrT^T -> f32 [T][768]
  gemm_bt_kernel<false, false><<<dim3(T_ / 128, Cc / 128), 256, 0, stream>>>(
      xeg, BrT, nullptr, out, KR, Cc);

  aux_kernel<<<1, 64, 0, stream>>>(stats, out, out_size);
}

// Round 3
// 459.284 us; speedup vs baseline: 2.2051x; 1.0839x over previous
//
#include <hip/hip_runtime.h>

// Problem constants
#define T_  4096
#define Bb  2
#define Nn  2048
#define Cc  768
#define Ee  24
#define Dd  64
#define Hh  12
#define KR  1568   // reduce GEMM K: 1536 (W_out) + 24 (b_out via dense gates) + 8 pad
#define KS  16     // gate k-split
#define KC  48     // 768 / KS

typedef __attribute__((ext_vector_type(8))) short bf16x8;
typedef __attribute__((ext_vector_type(4))) float f32x4;

__device__ __forceinline__ unsigned short f2bf(float f) {
  union { float f; unsigned int i; } u; u.f = f;
  unsigned int r = u.i + 0x7FFFu + ((u.i >> 16) & 1u);
  return (unsigned short)(r >> 16);
}
__device__ __forceinline__ float bf2f(unsigned short s) {
  union { unsigned int i; float f; } u; u.i = ((unsigned int)s) << 16; return u.f;
}

__device__ __forceinline__ void gload16(const void* g, void* l) {
  __builtin_amdgcn_global_load_lds(
      (const __attribute__((address_space(1))) void*)g,
      (__attribute__((address_space(3))) void*)l, 16, 0, 0);
}

// ---------------------------------------------------------------------------
// Conversion kernels (weights -> bf16 B^T layouts, x -> bf16)
// ---------------------------------------------------------------------------
__global__ __launch_bounds__(256) void convert_x_kernel(
    const float* __restrict__ x, unsigned short* __restrict__ xb)
{
  int i = blockIdx.x * 256 + threadIdx.x;          // one float4 each
  float4 v = ((const float4*)x)[i];
  ushort4 o;
  o.x = f2bf(v.x); o.y = f2bf(v.y); o.z = f2bf(v.z); o.w = f2bf(v.w);
  ((ushort4*)xb)[i] = o;
}

// W_in [E][C][D] -> BqT [E*D][C] bf16  (per-expert transpose)
__global__ __launch_bounds__(256) void convert_win_kernel(
    const float* __restrict__ W_in, unsigned short* __restrict__ BqT)
{
  __shared__ float ls[64][65];
  const int e = blockIdx.x, c0 = blockIdx.y * 64, tid = threadIdx.x;
  #pragma unroll
  for (int i = 0; i < 16; ++i) {
    int L = tid + i * 256, c = L >> 6, d = L & 63;
    ls[c][d] = W_in[(size_t)e * Cc * Dd + (size_t)(c0 + c) * Dd + d];
  }
  __syncthreads();
  #pragma unroll
  for (int i = 0; i < 16; ++i) {
    int L = tid + i * 256, d = L >> 6, c = L & 63;
    BqT[(size_t)(e * Dd + d) * Cc + c0 + c] = f2bf(ls[c][d]);
  }
}

// [W_out ; b_out ; 0] -> BrT [768][KR] bf16
__global__ __launch_bounds__(256) void convert_wout_kernel(
    const float* __restrict__ W_out, const float* __restrict__ b_out,
    unsigned short* __restrict__ BrT)
{
  __shared__ float ls[32][65];
  const int k0 = blockIdx.x * 32, n0 = blockIdx.y * 64, tid = threadIdx.x;
  #pragma unroll
  for (int i = 0; i < 8; ++i) {
    int L = tid + i * 256, k = L >> 6, n = L & 63;
    int kk = k0 + k;
    float v = (kk < 1536) ? W_out[(size_t)kk * Cc + n0 + n]
            : (kk < 1560) ? b_out[(size_t)(kk - 1536) * Cc + n0 + n] : 0.f;
    ls[k][n] = v;
  }
  __syncthreads();
  #pragma unroll
  for (int i = 0; i < 8; ++i) {
    int L = tid + i * 256, n = L >> 5, k = L & 31;
    BrT[(size_t)(n0 + n) * KR + k0 + k] = f2bf(ls[k][n]);
  }
}

// W_kv [C][128] -> BkvT [128][C] bf16
__global__ __launch_bounds__(256) void convert_wkv_kernel(
    const float* __restrict__ W_kv, unsigned short* __restrict__ BkvT)
{
  __shared__ float ls[64][129];
  const int c0 = blockIdx.x * 64, tid = threadIdx.x;
  #pragma unroll
  for (int i = 0; i < 32; ++i) {
    int L = tid + i * 256, c = L >> 7, j = L & 127;
    ls[c][j] = W_kv[(size_t)(c0 + c) * 128 + j];
  }
  __syncthreads();
  #pragma unroll
  for (int i = 0; i < 32; ++i) {
    int L = tid + i * 256, j = L >> 6, c = L & 63;
    BkvT[(size_t)j * Cc + c0 + c] = f2bf(ls[c][j]);
  }
}

// ---------------------------------------------------------------------------
// bf16 MFMA GEMM (m97 structure): C[M][N] = A[M][K]bf16 @ BT[N][K]bf16^T (+bias)
// 128x128 tile, BK=32, 4 waves each 64x64, global_load_lds width-16 staging.
// ---------------------------------------------------------------------------
template<bool BF16OUT, bool HASBIAS>
__global__ __launch_bounds__(256) void gemm_bt_kernel(
    const unsigned short* __restrict__ A, const unsigned short* __restrict__ BT,
    const float* __restrict__ bias, void* __restrict__ Cout, int K, int ldc)
{
  __shared__ __align__(16) unsigned short As[128 * 32];
  __shared__ __align__(16) unsigned short Bs[128 * 32];
  const int tid = threadIdx.x, w = tid >> 6, lane = tid & 63;
  const int quad = lane >> 4, nl = lane & 15;
  const int m0 = blockIdx.x * 128, n0 = blockIdx.y * 128;
  const int mw = (w & 1) * 64, nw = (w >> 1) * 64;

  f32x4 acc[4][4];
  #pragma unroll
  for (int i = 0; i < 4; ++i)
    #pragma unroll
    for (int j = 0; j < 4; ++j) acc[i][j] = (f32x4){0.f, 0.f, 0.f, 0.f};

  const int row0 = w * 32 + (lane >> 2);
  const int col8 = (lane & 3) * 8;
  const unsigned short* a0 = A + (size_t)(m0 + row0) * K + col8;
  const unsigned short* a1 = a0 + (size_t)16 * K;
  const unsigned short* b0 = BT + (size_t)(n0 + row0) * K + col8;
  const unsigned short* b1 = b0 + (size_t)16 * K;
  unsigned short* lA0 = As + (w * 32) * 32;
  unsigned short* lA1 = As + (w * 32 + 16) * 32;
  unsigned short* lB0 = Bs + (w * 32) * 32;
  unsigned short* lB1 = Bs + (w * 32 + 16) * 32;

  for (int k0 = 0; k0 < K; k0 += 32) {
    gload16(a0 + k0, lA0);
    gload16(a1 + k0, lA1);
    gload16(b0 + k0, lB0);
    gload16(b1 + k0, lB1);
    __syncthreads();

    bf16x8 af[4], bfr[4];
    #pragma unroll
    for (int mi = 0; mi < 4; ++mi)
      af[mi] = *(const bf16x8*)&As[(mw + mi * 16 + nl) * 32 + quad * 8];
    #pragma unroll
    for (int ni = 0; ni < 4; ++ni)
      bfr[ni] = *(const bf16x8*)&Bs[(nw + ni * 16 + nl) * 32 + quad * 8];
    #pragma unroll
    for (int mi = 0; mi < 4; ++mi)
      #pragma unroll
      for (int ni = 0; ni < 4; ++ni)
        acc[mi][ni] = __builtin_amdgcn_mfma_f32_16x16x32_bf16(
            af[mi], bfr[ni], acc[mi][ni], 0, 0, 0);
    __syncthreads();
  }

  #pragma unroll
  for (int mi = 0; mi < 4; ++mi) {
    int rowb = m0 + mw + mi * 16 + quad * 4;
    #pragma unroll
    for (int ni = 0; ni < 4; ++ni) {
      int col = n0 + nw + ni * 16 + nl;
      float bv = HASBIAS ? bias[col] : 0.f;
      #pragma unroll
      for (int reg = 0; reg < 4; ++reg) {
        float v = acc[mi][ni][reg] + bv;
        if (BF16OUT)
          ((unsigned short*)Cout)[(size_t)(rowb + reg) * ldc + col] = f2bf(v);
        else
          ((float*)Cout)[(size_t)(rowb + reg) * ldc + col] = v;
      }
    }
  }
}

// ---------------------------------------------------------------------------
// gate1: partial logits.  Token-per-thread, k-split.
// grid (T/256, KS); block 256.  partial[t][s][e] f32.
// ---------------------------------------------------------------------------
#define XPAD 52    // row stride (floats) for xs: mult of 4 (16B align), non-pow2
__global__ __launch_bounds__(256) void gate1_kernel(
    const float* __restrict__ x, const float* __restrict__ wg,
    float* __restrict__ partial)
{
  __shared__ __align__(16) float xs[256 * XPAD];   // 53,248 B
  __shared__ __align__(16) float wsT[Ee * KC];     //  4,608 B
  const int tid = threadIdx.x;
  const int t0 = blockIdx.x * 256;
  const int s = blockIdx.y, k0 = s * KC;

  // stage x tile [256 tokens][48 k]: 3072 float4, 12 per thread
  #pragma unroll
  for (int i = 0; i < 12; ++i) {
    int f = tid + i * 256;
    int token = f / 12, j = f % 12;
    float4 v = *(const float4*)&x[(size_t)(t0 + token) * Cc + k0 + j * 4];
    *(float4*)&xs[token * XPAD + j * 4] = v;
  }
  // stage wg slice transposed: wsT[e][kk]
  for (int i = tid; i < Ee * KC; i += 256)
    wsT[(i % Ee) * KC + i / Ee] = wg[k0 * Ee + i];
  __syncthreads();

  float xr[KC];
  #pragma unroll
  for (int kg = 0; kg < KC / 4; ++kg)
    *(float4*)&xr[kg * 4] = *(const float4*)&xs[tid * XPAD + kg * 4];

  float acc[Ee];
  #pragma unroll
  for (int e = 0; e < Ee; ++e) acc[e] = 0.f;
  #pragma unroll
  for (int e = 0; e < Ee; ++e) {
    #pragma unroll
    for (int kg = 0; kg < KC / 4; ++kg) {
      float4 wv = *(const float4*)&wsT[e * KC + kg * 4];  // broadcast read
      acc[e] += xr[kg * 4 + 0] * wv.x + xr[kg * 4 + 1] * wv.y
              + xr[kg * 4 + 2] * wv.z + xr[kg * 4 + 3] * wv.w;
    }
  }

  float* dst = partial + ((size_t)(t0 + tid) * KS + s) * Ee;
  #pragma unroll
  for (int eg = 0; eg < Ee / 4; ++eg)
    *(float4*)&dst[eg * 4] = *(float4*)&acc[eg * 4];
}

// ---------------------------------------------------------------------------
// gate2: sum partials -> logits; softmax; top-12; gates; aux-loss atomics.
// One wave per token. stats: [0..23] p_sum, [24..47] freqs, [48] z_sum
// ---------------------------------------------------------------------------
__global__ __launch_bounds__(256) void gate2_kernel(
    const float* __restrict__ partial,
    int* __restrict__ idx, float* __restrict__ gate, float* __restrict__ stats)
{
  const int tid = threadIdx.x;
  const int w = tid >> 6, lane = tid & 63;
  const int t = blockIdx.x * 4 + w;

  float logit = -1e30f;
  if (lane < Ee) {
    const float* p = partial + (size_t)t * KS * Ee + lane;
    float acc = 0.f;
    #pragma unroll
    for (int s = 0; s < KS; ++s) acc += p[s * Ee];
    logit = acc;
  }
  float m = logit;
  for (int o = 32; o; o >>= 1) m = fmaxf(m, __shfl_xor(m, o));
  float p = (lane < Ee) ? expf(logit - m) : 0.f;
  float s = p;
  for (int o = 32; o; o >>= 1) s += __shfl_xor(s, o);
  float prob = p / s;
  float lse = m + logf(s);
  if (lane == 0) atomicAdd(&stats[48], lse * lse);
  if (lane < Ee) atomicAdd(&stats[lane], prob);

  bool sel = false;
  float my_p = 0.f; int my_e = -1;
  for (int h = 0; h < Hh; ++h) {
    float v = (lane < Ee && !sel) ? prob : -1.f;
    int ix = lane;
    for (int o = 32; o; o >>= 1) {
      float ov = __shfl_xor(v, o); int oi = __shfl_xor(ix, o);
      if (ov > v || (ov == v && oi < ix)) { v = ov; ix = oi; }
    }
    if (lane == ix) sel = true;
    if (lane == h) { my_p = v; my_e = ix; }
  }
  float gsum = (lane < Hh) ? my_p : 0.f;
  for (int o = 32; o; o >>= 1) gsum += __shfl_xor(gsum, o);
  if (lane < Hh) {
    idx[t * Hh + lane] = my_e;
    gate[t * Hh + lane] = my_p / (gsum + 1e-6f);
    atomicAdd(&stats[24 + my_e], 1.0f);
  }
}

// ---------------------------------------------------------------------------
// Gather selected q (bf16 -> bf16) into [B,H,N,D]
// ---------------------------------------------------------------------------
__global__ __launch_bounds__(256) void gatherq_kernel(
    const unsigned short* __restrict__ qallb, const int* __restrict__ idx,
    unsigned short* __restrict__ qh)
{
  const int t = blockIdx.x, b = t >> 11, nn = t & (Nn - 1);
  for (int i = threadIdx.x; i < Hh * Dd; i += 256) {
    int h = i >> 6, d = i & 63;
    int e = idx[t * Hh + h];
    qh[((size_t)(b * Hh + h) * Nn + nn) * Dd + d] =
        qallb[(size_t)t * (Ee * Dd) + e * Dd + d];
  }
}

// ---------------------------------------------------------------------------
// Flash attention, MFMA 16x16x32 bf16.  kvbuf packed [T][128]: k 0..63, v 64..127
// ---------------------------------------------------------------------------
#define PADK 72
__global__ __launch_bounds__(256) void attn_kernel(
    const unsigned short* __restrict__ qh, const unsigned short* __restrict__ kvbuf,
    float* __restrict__ obuf)
{
  __shared__ __align__(16) unsigned short ks[64 * PADK];   // [key][d]
  __shared__ __align__(16) unsigned short vT[64 * PADK];   // [d][key]
  __shared__ __align__(16) unsigned short pl[4 * 16 * PADK]; // per-wave P [q][key]

  const int tid = threadIdx.x;
  const int w = tid >> 6, lane = tid & 63;
  const int quad = lane >> 4, nl = lane & 15;
  const int bh = blockIdx.y;
  const int b = bh / Hh;
  const int i0 = blockIdx.x * 64;

  const unsigned short* qrow = qh + ((size_t)(bh * Nn + i0 + w * 16 + nl)) * Dd;
  bf16x8 qA0 = *(const bf16x8*)(qrow + quad * 8);
  bf16x8 qA1 = *(const bf16x8*)(qrow + 32 + quad * 8);

  f32x4 acc[4];
  #pragma unroll
  for (int f = 0; f < 4; ++f) acc[f] = (f32x4){0.f, 0.f, 0.f, 0.f};
  float m_r[4] = {-1e30f, -1e30f, -1e30f, -1e30f};
  float l_r[4] = {0.f, 0.f, 0.f, 0.f};
  unsigned short* plw = pl + w * 16 * PADK;

  for (int j0 = 0; j0 < Nn; j0 += 64) {
    const unsigned short* kb = kvbuf + ((size_t)(b * Nn + j0)) * 128;
    #pragma unroll
    for (int it = 0; it < 16; ++it) {
      int L = tid + it * 256;
      int key = L >> 6, d = L & 63;
      ks[key * PADK + d] = kb[key * 128 + d];
      vT[d * PADK + key] = kb[key * 128 + 64 + d];
    }
    __syncthreads();

    f32x4 sv[4];
    #pragma unroll
    for (int kg = 0; kg < 4; ++kg) {
      const unsigned short* kr = ks + (kg * 16 + nl) * PADK;
      bf16x8 b0 = *(const bf16x8*)(kr + quad * 8);
      bf16x8 b1 = *(const bf16x8*)(kr + 32 + quad * 8);
      f32x4 c = {0.f, 0.f, 0.f, 0.f};
      c = __builtin_amdgcn_mfma_f32_16x16x32_bf16(qA0, b0, c, 0, 0, 0);
      c = __builtin_amdgcn_mfma_f32_16x16x32_bf16(qA1, b1, c, 0, 0, 0);
      sv[kg] = c;
    }

    #pragma unroll
    for (int reg = 0; reg < 4; ++reg) {
      float s[4];
      #pragma unroll
      for (int kg = 0; kg < 4; ++kg) s[kg] = sv[kg][reg] * 0.125f;
      float loc = fmaxf(fmaxf(s[0], s[1]), fmaxf(s[2], s[3]));
      loc = fmaxf(loc, __shfl_xor(loc, 1));
      loc = fmaxf(loc, __shfl_xor(loc, 2));
      loc = fmaxf(loc, __shfl_xor(loc, 4));
      loc = fmaxf(loc, __shfl_xor(loc, 8));
      float mx = fmaxf(m_r[reg], loc);
      float alpha = __expf(m_r[reg] - mx);
      m_r[reg] = mx;
      float ls = 0.f;
      unsigned short us[4];
      #pragma unroll
      for (int kg = 0; kg < 4; ++kg) {
        float p = __expf(s[kg] - mx);
        us[kg] = f2bf(p);
        ls += bf2f(us[kg]);
      }
      ls += __shfl_xor(ls, 1);
      ls += __shfl_xor(ls, 2);
      ls += __shfl_xor(ls, 4);
      ls += __shfl_xor(ls, 8);
      l_r[reg] = l_r[reg] * alpha + ls;
      #pragma unroll
      for (int f = 0; f < 4; ++f) acc[f][reg] *= alpha;
      unsigned short* pr = plw + (quad * 4 + reg) * PADK + nl;
      pr[0] = us[0]; pr[16] = us[1]; pr[32] = us[2]; pr[48] = us[3];
    }
    bf16x8 pA0 = *(const bf16x8*)(plw + nl * PADK + quad * 8);
    bf16x8 pA1 = *(const bf16x8*)(plw + nl * PADK + 32 + quad * 8);
    #pragma unroll
    for (int f = 0; f < 4; ++f) {
      const unsigned short* vr = vT + (f * 16 + nl) * PADK;
      bf16x8 v0 = *(const bf16x8*)(vr + quad * 8);
      bf16x8 v1 = *(const bf16x8*)(vr + 32 + quad * 8);
      acc[f] = __builtin_amdgcn_mfma_f32_16x16x32_bf16(pA0, v0, acc[f], 0, 0, 0);
      acc[f] = __builtin_amdgcn_mfma_f32_16x16x32_bf16(pA1, v1, acc[f], 0, 0, 0);
    }
    __syncthreads();
  }

  float* orow = obuf + ((size_t)(bh * Nn + i0 + w * 16)) * Dd;
  #pragma unroll
  for (int f = 0; f < 4; ++f)
    #pragma unroll
    for (int reg = 0; reg < 4; ++reg)
      orow[(quad * 4 + reg) * Dd + f * 16 + nl] = acc[f][reg] / l_r[reg];
}

// ---------------------------------------------------------------------------
// Scatter gated o into dense bf16 xeg[T][KR]
// ---------------------------------------------------------------------------
__global__ __launch_bounds__(256) void scatter_kernel(
    const float* __restrict__ obuf, const int* __restrict__ idx,
    const float* __restrict__ gate, unsigned short* __restrict__ xeg)
{
  const int t = blockIdx.x, b = t >> 11, nn = t & (Nn - 1);
  for (int i = threadIdx.x; i < Hh * Dd; i += 256) {
    int h = i >> 6, d = i & 63;
    int e = idx[t * Hh + h];
    float g = gate[t * Hh + h];
    xeg[(size_t)t * KR + e * Dd + d] =
        f2bf(g * obuf[((size_t)(b * Hh + h) * Nn + nn) * Dd + d]);
  }
  if (threadIdx.x < Hh) {
    int e = idx[t * Hh + threadIdx.x];
    xeg[(size_t)t * KR + 1536 + e] = f2bf(gate[t * Hh + threadIdx.x]);
  }
}

// ---------------------------------------------------------------------------
// Aux loss finalize
// ---------------------------------------------------------------------------
__global__ void aux_kernel(const float* __restrict__ stats,
                           float* __restrict__ out, int out_size)
{
  if (threadIdx.x == 0 && blockIdx.x == 0) {
    float pt = 0.f, ft = 0.f, sw = 0.f;
    for (int e = 0; e < Ee; ++e) { pt += stats[e]; ft += stats[24 + e]; }
    for (int e = 0; e < Ee; ++e) sw += stats[e] * stats[24 + e];
    float sswitch = (float)Ee * sw / (pt * ft);
    float z = stats[48] * (1.0f / (float)T_);
    out[out_size - 1] = 0.1f * sswitch + 0.001f * z;
  }
}

// ---------------------------------------------------------------------------
extern "C" void kernel_launch(void* const* d_in, const int* in_sizes, int n_in,
                              void* d_out, int out_size, void* d_ws, size_t ws_size,
                              hipStream_t stream)
{
  const float* x     = (const float*)d_in[0];
  const float* wg    = (const float*)d_in[1];
  const float* W_in  = (const float*)d_in[2];
  const float* b_in  = (const float*)d_in[3];
  const float* W_out = (const float*)d_in[4];
  const float* b_out = (const float*)d_in[5];
  const float* W_kv  = (const float*)d_in[6];
  const float* b_kv  = (const float*)d_in[7];
  float* out = (float*)d_out;

  char* ws = (char*)d_ws;
  size_t off = 0;
  auto carve = [&](size_t bytes) -> void* {
    void* p = ws + off;
    off = (off + bytes + 255) & ~(size_t)255;
    return p;
  };
  int*            idx   = (int*)           carve((size_t)T_ * Hh * 4);
  float*          gate  = (float*)         carve((size_t)T_ * Hh * 4);
  float*          stats = (float*)         carve(256);
  float*          lpart = (float*)         carve((size_t)T_ * KS * Ee * 4);
  unsigned short* xb    = (unsigned short*)carve((size_t)T_ * Cc * 2);
  unsigned short* BqT   = (unsigned short*)carve((size_t)Ee * Dd * Cc * 2);
  unsigned short* BrT   = (unsigned short*)carve((size_t)Cc * KR * 2);
  unsigned short* BkvT  = (unsigned short*)carve((size_t)128 * Cc * 2);
  unsigned short* kvbuf = (unsigned short*)carve((size_t)T_ * 128 * 2);
  unsigned short* qallb = (unsigned short*)carve((size_t)T_ * Ee * Dd * 2);
  unsigned short* qh    = (unsigned short*)carve((size_t)T_ * Hh * Dd * 2);
  float*          obuf  = (float*)         carve((size_t)T_ * Hh * Dd * 4);
  unsigned short* xeg   = (unsigned short*)carve((size_t)T_ * KR * 2);

  hipMemsetAsync(stats, 0, 256, stream);
  hipMemsetAsync(xeg, 0, (size_t)T_ * KR * 2, stream);

  // conversions
  convert_x_kernel  <<<T_ * Cc / 4 / 256, 256, 0, stream>>>(x, xb);
  convert_win_kernel<<<dim3(Ee, Cc / 64), 256, 0, stream>>>(W_in, BqT);
  convert_wout_kernel<<<dim3(KR / 32, Cc / 64), 256, 0, stream>>>(W_out, b_out, BrT);
  convert_wkv_kernel<<<Cc / 64, 256, 0, stream>>>(W_kv, BkvT);

  // gating
  gate1_kernel<<<dim3(T_ / 256, KS), 256, 0, stream>>>(x, wg, lpart);
  gate2_kernel<<<T_ / 4, 256, 0, stream>>>(lpart, idx, gate, stats);

  // kv = xb @ BkvT^T + b_kv  -> bf16 [T][128]
  gemm_bt_kernel<true, true><<<dim3(T_ / 128, 1), 256, 0, stream>>>(
      xb, BkvT, b_kv, kvbuf, Cc, 128);
  // q_all = xb @ BqT^T + b_in -> bf16 [T][1536]
  gemm_bt_kernel<true, true><<<dim3(T_ / 128, Ee * Dd / 128), 256, 0, stream>>>(
      xb, BqT, b_in, qallb, Cc, Ee * Dd);

  gatherq_kernel<<<T_, 256, 0, stream>>>(qallb, idx, qh);
  attn_kernel<<<dim3(Nn / 64, Bb * Hh), 256, 0, stream>>>(qh, kvbuf, obuf);
  scatter_kernel<<<T_, 256, 0, stream>>>(obuf, idx, gate, xeg);

  // out = xeg @ BrT^T -> f32 [T][768]
  gemm_bt_kernel<false, false><<<dim3(T_ / 128, Cc / 128), 256, 0, stream>>>(
      xeg, BrT, nullptr, out, KR, Cc);

  aux_kernel<<<1, 64, 0, stream>>>(stats, out, out_size);
}

// Round 4
// 373.510 us; speedup vs baseline: 2.7115x; 1.2296x over previous
//
#include <hip/hip_runtime.h>

// Problem constants
#define T_  4096
#define Bb  2
#define Nn  2048
#define Cc  768
#define Ee  24
#define Dd  64
#define Hh  12
#define KR  1568   // reduce GEMM K: 1536 (W_out) + 24 (b_out via dense gates) + 8 pad
#define KS  16     // gate k-split
#define KC  48     // 768 / KS
#define NB2 1024   // gate2 block count (T_/4)

typedef __attribute__((ext_vector_type(8))) short bf16x8;
typedef __attribute__((ext_vector_type(4))) float f32x4;

__device__ __forceinline__ unsigned short f2bf(float f) {
  union { float f; unsigned int i; } u; u.f = f;
  unsigned int r = u.i + 0x7FFFu + ((u.i >> 16) & 1u);
  return (unsigned short)(r >> 16);
}
__device__ __forceinline__ float bf2f(unsigned short s) {
  union { unsigned int i; float f; } u; u.i = ((unsigned int)s) << 16; return u.f;
}

__device__ __forceinline__ void gload16(const void* g, void* l) {
  __builtin_amdgcn_global_load_lds(
      (const __attribute__((address_space(1))) void*)g,
      (__attribute__((address_space(3))) void*)l, 16, 0, 0);
}

// ---------------------------------------------------------------------------
// Conversion kernels (weights -> bf16 B^T layouts, x -> bf16)
// ---------------------------------------------------------------------------
__global__ __launch_bounds__(256) void convert_x_kernel(
    const float* __restrict__ x, unsigned short* __restrict__ xb)
{
  int i = blockIdx.x * 256 + threadIdx.x;          // one float4 each
  float4 v = ((const float4*)x)[i];
  ushort4 o;
  o.x = f2bf(v.x); o.y = f2bf(v.y); o.z = f2bf(v.z); o.w = f2bf(v.w);
  ((ushort4*)xb)[i] = o;
}

// W_in [E][C][D] -> BqT [E*D][C] bf16  (per-expert transpose)
__global__ __launch_bounds__(256) void convert_win_kernel(
    const float* __restrict__ W_in, unsigned short* __restrict__ BqT)
{
  __shared__ float ls[64][65];
  const int e = blockIdx.x, c0 = blockIdx.y * 64, tid = threadIdx.x;
  #pragma unroll
  for (int i = 0; i < 16; ++i) {
    int L = tid + i * 256, c = L >> 6, d = L & 63;
    ls[c][d] = W_in[(size_t)e * Cc * Dd + (size_t)(c0 + c) * Dd + d];
  }
  __syncthreads();
  #pragma unroll
  for (int i = 0; i < 16; ++i) {
    int L = tid + i * 256, d = L >> 6, c = L & 63;
    BqT[(size_t)(e * Dd + d) * Cc + c0 + c] = f2bf(ls[c][d]);
  }
}

// [W_out ; b_out ; 0] -> BrT [768][KR] bf16
__global__ __launch_bounds__(256) void convert_wout_kernel(
    const float* __restrict__ W_out, const float* __restrict__ b_out,
    unsigned short* __restrict__ BrT)
{
  __shared__ float ls[32][65];
  const int k0 = blockIdx.x * 32, n0 = blockIdx.y * 64, tid = threadIdx.x;
  #pragma unroll
  for (int i = 0; i < 8; ++i) {
    int L = tid + i * 256, k = L >> 6, n = L & 63;
    int kk = k0 + k;
    float v = (kk < 1536) ? W_out[(size_t)kk * Cc + n0 + n]
            : (kk < 1560) ? b_out[(size_t)(kk - 1536) * Cc + n0 + n] : 0.f;
    ls[k][n] = v;
  }
  __syncthreads();
  #pragma unroll
  for (int i = 0; i < 8; ++i) {
    int L = tid + i * 256, n = L >> 5, k = L & 31;
    BrT[(size_t)(n0 + n) * KR + k0 + k] = f2bf(ls[k][n]);
  }
}

// W_kv [C][128] -> BkvT [128][C] bf16
__global__ __launch_bounds__(256) void convert_wkv_kernel(
    const float* __restrict__ W_kv, unsigned short* __restrict__ BkvT)
{
  __shared__ float ls[64][129];
  const int c0 = blockIdx.x * 64, tid = threadIdx.x;
  #pragma unroll
  for (int i = 0; i < 32; ++i) {
    int L = tid + i * 256, c = L >> 7, j = L & 127;
    ls[c][j] = W_kv[(size_t)(c0 + c) * 128 + j];
  }
  __syncthreads();
  #pragma unroll
  for (int i = 0; i < 32; ++i) {
    int L = tid + i * 256, j = L >> 6, c = L & 63;
    BkvT[(size_t)j * Cc + c0 + c] = f2bf(ls[c][j]);
  }
}

// ---------------------------------------------------------------------------
// bf16 MFMA GEMM (m97 structure): C = A[M][K] @ BT[N][K]^T (+bias)
// MODE 0: f32 out, no bias.  MODE 1: bf16 out + bias.
// MODE 2: kv special — cols 0..63 -> K [B][N][D], cols 64..127 -> V^T [B][D][N]
// ---------------------------------------------------------------------------
template<int MODE>
__global__ __launch_bounds__(256) void gemm_bt_kernel(
    const unsigned short* __restrict__ A, const unsigned short* __restrict__ BT,
    const float* __restrict__ bias, void* __restrict__ Cout,
    void* __restrict__ Cout2, int K, int ldc)
{
  __shared__ __align__(16) unsigned short As[128 * 32];
  __shared__ __align__(16) unsigned short Bs[128 * 32];
  const int tid = threadIdx.x, w = tid >> 6, lane = tid & 63;
  const int quad = lane >> 4, nl = lane & 15;
  const int m0 = blockIdx.x * 128, n0 = blockIdx.y * 128;
  const int mw = (w & 1) * 64, nw = (w >> 1) * 64;

  f32x4 acc[4][4];
  #pragma unroll
  for (int i = 0; i < 4; ++i)
    #pragma unroll
    for (int j = 0; j < 4; ++j) acc[i][j] = (f32x4){0.f, 0.f, 0.f, 0.f};

  const int row0 = w * 32 + (lane >> 2);
  const int col8 = (lane & 3) * 8;
  const unsigned short* a0 = A + (size_t)(m0 + row0) * K + col8;
  const unsigned short* a1 = a0 + (size_t)16 * K;
  const unsigned short* b0 = BT + (size_t)(n0 + row0) * K + col8;
  const unsigned short* b1 = b0 + (size_t)16 * K;
  unsigned short* lA0 = As + (w * 32) * 32;
  unsigned short* lA1 = As + (w * 32 + 16) * 32;
  unsigned short* lB0 = Bs + (w * 32) * 32;
  unsigned short* lB1 = Bs + (w * 32 + 16) * 32;

  for (int k0 = 0; k0 < K; k0 += 32) {
    gload16(a0 + k0, lA0);
    gload16(a1 + k0, lA1);
    gload16(b0 + k0, lB0);
    gload16(b1 + k0, lB1);
    __syncthreads();

    bf16x8 af[4], bfr[4];
    #pragma unroll
    for (int mi = 0; mi < 4; ++mi)
      af[mi] = *(const bf16x8*)&As[(mw + mi * 16 + nl) * 32 + quad * 8];
    #pragma unroll
    for (int ni = 0; ni < 4; ++ni)
      bfr[ni] = *(const bf16x8*)&Bs[(nw + ni * 16 + nl) * 32 + quad * 8];
    #pragma unroll
    for (int mi = 0; mi < 4; ++mi)
      #pragma unroll
      for (int ni = 0; ni < 4; ++ni)
        acc[mi][ni] = __builtin_amdgcn_mfma_f32_16x16x32_bf16(
            af[mi], bfr[ni], acc[mi][ni], 0, 0, 0);
    __syncthreads();
  }

  #pragma unroll
  for (int mi = 0; mi < 4; ++mi) {
    int rowb = m0 + mw + mi * 16 + quad * 4;
    int bb = rowb >> 11, nn = rowb & (Nn - 1);   // used by MODE 2
    #pragma unroll
    for (int ni = 0; ni < 4; ++ni) {
      int col = n0 + nw + ni * 16 + nl;
      float bv = (MODE != 0) ? bias[col] : 0.f;
      if (MODE == 2) {
        if (col < Dd) {
          #pragma unroll
          for (int reg = 0; reg < 4; ++reg)
            ((unsigned short*)Cout)[((size_t)bb * Nn + nn + reg) * Dd + col] =
                f2bf(acc[mi][ni][reg] + bv);
        } else {
          ushort4 v;
          v.x = f2bf(acc[mi][ni][0] + bv);
          v.y = f2bf(acc[mi][ni][1] + bv);
          v.z = f2bf(acc[mi][ni][2] + bv);
          v.w = f2bf(acc[mi][ni][3] + bv);
          *(ushort4*)((unsigned short*)Cout2 +
                      ((size_t)bb * Dd + (col - Dd)) * Nn + nn) = v;
        }
      } else {
        #pragma unroll
        for (int reg = 0; reg < 4; ++reg) {
          float v = acc[mi][ni][reg] + bv;
          if (MODE == 1)
            ((unsigned short*)Cout)[(size_t)(rowb + reg) * ldc + col] = f2bf(v);
          else
            ((float*)Cout)[(size_t)(rowb + reg) * ldc + col] = v;
        }
      }
    }
  }
}

// ---------------------------------------------------------------------------
// gate1: partial logits.  Token-per-thread, k-split.
// grid (T/256, KS); block 256.  partial[t][s][e] f32.
// ---------------------------------------------------------------------------
#define XPAD 52    // row stride (floats) for xs: mult of 4 (16B align), non-pow2
__global__ __launch_bounds__(256) void gate1_kernel(
    const float* __restrict__ x, const float* __restrict__ wg,
    float* __restrict__ partial)
{
  __shared__ __align__(16) float xs[256 * XPAD];   // 53,248 B
  __shared__ __align__(16) float wsT[Ee * KC];     //  4,608 B
  const int tid = threadIdx.x;
  const int t0 = blockIdx.x * 256;
  const int s = blockIdx.y, k0 = s * KC;

  #pragma unroll
  for (int i = 0; i < 12; ++i) {
    int f = tid + i * 256;
    int token = f / 12, j = f % 12;
    float4 v = *(const float4*)&x[(size_t)(t0 + token) * Cc + k0 + j * 4];
    *(float4*)&xs[token * XPAD + j * 4] = v;
  }
  for (int i = tid; i < Ee * KC; i += 256)
    wsT[(i % Ee) * KC + i / Ee] = wg[k0 * Ee + i];
  __syncthreads();

  float xr[KC];
  #pragma unroll
  for (int kg = 0; kg < KC / 4; ++kg)
    *(float4*)&xr[kg * 4] = *(const float4*)&xs[tid * XPAD + kg * 4];

  float acc[Ee];
  #pragma unroll
  for (int e = 0; e < Ee; ++e) acc[e] = 0.f;
  #pragma unroll
  for (int e = 0; e < Ee; ++e) {
    #pragma unroll
    for (int kg = 0; kg < KC / 4; ++kg) {
      float4 wv = *(const float4*)&wsT[e * KC + kg * 4];  // broadcast read
      acc[e] += xr[kg * 4 + 0] * wv.x + xr[kg * 4 + 1] * wv.y
              + xr[kg * 4 + 2] * wv.z + xr[kg * 4 + 3] * wv.w;
    }
  }

  float* dst = partial + ((size_t)(t0 + tid) * KS + s) * Ee;
  #pragma unroll
  for (int eg = 0; eg < Ee / 4; ++eg)
    *(float4*)&dst[eg * 4] = *(float4*)&acc[eg * 4];
}

// ---------------------------------------------------------------------------
// gate2: logits (coalesced via LDS) -> softmax -> top-12 -> gates.
// Block stats in LDS -> bstats[49][NB2] (NO global atomics; deterministic).
// bstats rows: 0..23 p_sum, 24..47 freqs, 48 z_sum
// ---------------------------------------------------------------------------
__global__ __launch_bounds__(256) void gate2_kernel(
    const float* __restrict__ partial,
    int* __restrict__ idx, float* __restrict__ gate, float* __restrict__ bstats)
{
  __shared__ float xls[4][KS * Ee];   // 4 waves x 384
  __shared__ float sacc[49];
  const int tid = threadIdx.x;
  const int w = tid >> 6, lane = tid & 63;
  const int t = blockIdx.x * 4 + w;

  if (tid < 49) sacc[tid] = 0.f;

  // cooperative coalesced load of this wave's 384 partials
  const float* p = partial + (size_t)t * (KS * Ee);
  #pragma unroll
  for (int i = 0; i < 6; ++i) xls[w][lane + i * 64] = p[lane + i * 64];
  // wave-internal LDS round-trip: DS pipe is in-order within a wave

  float logit = -1e30f;
  if (lane < Ee) {
    float acc = 0.f;
    #pragma unroll
    for (int s = 0; s < KS; ++s) acc += xls[w][s * Ee + lane];
    logit = acc;
  }
  float m = logit;
  for (int o = 32; o; o >>= 1) m = fmaxf(m, __shfl_xor(m, o));
  float pr = (lane < Ee) ? expf(logit - m) : 0.f;
  float s = pr;
  for (int o = 32; o; o >>= 1) s += __shfl_xor(s, o);
  float prob = pr / s;
  float lse = m + logf(s);

  bool sel = false;
  float my_p = 0.f; int my_e = -1;
  for (int h = 0; h < Hh; ++h) {
    float v = (lane < Ee && !sel) ? prob : -1.f;
    int ix = lane;
    for (int o = 32; o; o >>= 1) {
      float ov = __shfl_xor(v, o); int oi = __shfl_xor(ix, o);
      if (ov > v || (ov == v && oi < ix)) { v = ov; ix = oi; }
    }
    if (lane == ix) sel = true;
    if (lane == h) { my_p = v; my_e = ix; }
  }
  float gsum = (lane < Hh) ? my_p : 0.f;
  for (int o = 32; o; o >>= 1) gsum += __shfl_xor(gsum, o);
  if (lane < Hh) {
    idx[t * Hh + lane] = my_e;
    gate[t * Hh + lane] = my_p / (gsum + 1e-6f);
  }

  __syncthreads();                    // sacc zeroed before accumulation
  if (lane < Ee) atomicAdd(&sacc[lane], prob);           // LDS atomics
  if (lane < Hh) atomicAdd(&sacc[24 + my_e], 1.0f);
  if (lane == 0) atomicAdd(&sacc[48], lse * lse);
  __syncthreads();
  if (tid < 49) bstats[(size_t)tid * NB2 + blockIdx.x] = sacc[tid];
}

// ---------------------------------------------------------------------------
// Gather selected q (bf16 -> bf16) into [B,H,N,D]
// ---------------------------------------------------------------------------
__global__ __launch_bounds__(256) void gatherq_kernel(
    const unsigned short* __restrict__ qallb, const int* __restrict__ idx,
    unsigned short* __restrict__ qh)
{
  const int t = blockIdx.x, b = t >> 11, nn = t & (Nn - 1);
  for (int i = threadIdx.x; i < Hh * Dd; i += 256) {
    int h = i >> 6, d = i & 63;
    int e = idx[t * Hh + h];
    qh[((size_t)(b * Hh + h) * Nn + nn) * Dd + d] =
        qallb[(size_t)t * (Ee * Dd) + e * Dd + d];
  }
}

// ---------------------------------------------------------------------------
// Flash attention, MFMA 16x16x32 bf16.
// kbuf [B][N][D] bf16, vtbuf [B][D][N] bf16 (pre-transposed by kv GEMM).
// ---------------------------------------------------------------------------
#define PADK 72   // row stride (ushorts): 144 B, 16B-aligned
__global__ __launch_bounds__(256) void attn_kernel(
    const unsigned short* __restrict__ qh, const unsigned short* __restrict__ kbuf,
    const unsigned short* __restrict__ vtbuf, float* __restrict__ obuf)
{
  __shared__ __align__(16) unsigned short ks[64 * PADK];   // [key][d]
  __shared__ __align__(16) unsigned short vT[64 * PADK];   // [d][key]
  __shared__ __align__(16) unsigned short pl[4 * 16 * PADK]; // per-wave P [q][key]

  const int tid = threadIdx.x;
  const int w = tid >> 6, lane = tid & 63;
  const int quad = lane >> 4, nl = lane & 15;
  const int bh = blockIdx.y;
  const int b = bh / Hh;
  const int i0 = blockIdx.x * 64;

  const unsigned short* qrow = qh + ((size_t)(bh * Nn + i0 + w * 16 + nl)) * Dd;
  bf16x8 qA0 = *(const bf16x8*)(qrow + quad * 8);
  bf16x8 qA1 = *(const bf16x8*)(qrow + 32 + quad * 8);

  f32x4 acc[4];
  #pragma unroll
  for (int f = 0; f < 4; ++f) acc[f] = (f32x4){0.f, 0.f, 0.f, 0.f};
  float m_r[4] = {-1e30f, -1e30f, -1e30f, -1e30f};
  float l_r[4] = {0.f, 0.f, 0.f, 0.f};
  unsigned short* plw = pl + w * 16 * PADK;

  // staging coords: 512 16B-chunks per buffer pair, 2 per thread
  const int sr = tid >> 2;            // 0..63
  const int sc = (tid & 3) * 16;      // 0 or 16 or 32 or 48 (x2 chunks below)

  for (int j0 = 0; j0 < Nn; j0 += 64) {
    const unsigned short* kb  = kbuf  + ((size_t)b * Nn + j0) * Dd;
    const unsigned short* vtb = vtbuf + (size_t)b * Dd * Nn + j0;
    #pragma unroll
    for (int h2 = 0; h2 < 2; ++h2) {
      int c = sc + h2 * 8;            // column element offset within row
      *(bf16x8*)&ks[sr * PADK + c] = *(const bf16x8*)(kb + sr * Dd + c);
      *(bf16x8*)&vT[sr * PADK + c] = *(const bf16x8*)(vtb + (size_t)sr * Nn + c);
    }
    __syncthreads();

    f32x4 sv[4];
    #pragma unroll
    for (int kg = 0; kg < 4; ++kg) {
      const unsigned short* kr = ks + (kg * 16 + nl) * PADK;
      bf16x8 b0 = *(const bf16x8*)(kr + quad * 8);
      bf16x8 b1 = *(const bf16x8*)(kr + 32 + quad * 8);
      f32x4 c = {0.f, 0.f, 0.f, 0.f};
      c = __builtin_amdgcn_mfma_f32_16x16x32_bf16(qA0, b0, c, 0, 0, 0);
      c = __builtin_amdgcn_mfma_f32_16x16x32_bf16(qA1, b1, c, 0, 0, 0);
      sv[kg] = c;
    }

    #pragma unroll
    for (int reg = 0; reg < 4; ++reg) {
      float s[4];
      #pragma unroll
      for (int kg = 0; kg < 4; ++kg) s[kg] = sv[kg][reg] * 0.125f;
      float loc = fmaxf(fmaxf(s[0], s[1]), fmaxf(s[2], s[3]));
      loc = fmaxf(loc, __shfl_xor(loc, 1));
      loc = fmaxf(loc, __shfl_xor(loc, 2));
      loc = fmaxf(loc, __shfl_xor(loc, 4));
      loc = fmaxf(loc, __shfl_xor(loc, 8));
      float mx = fmaxf(m_r[reg], loc);
      float alpha = __expf(m_r[reg] - mx);
      m_r[reg] = mx;
      float ls = 0.f;
      unsigned short us[4];
      #pragma unroll
      for (int kg = 0; kg < 4; ++kg) {
        float p = __expf(s[kg] - mx);
        us[kg] = f2bf(p);
        ls += bf2f(us[kg]);
      }
      ls += __shfl_xor(ls, 1);
      ls += __shfl_xor(ls, 2);
      ls += __shfl_xor(ls, 4);
      ls += __shfl_xor(ls, 8);
      l_r[reg] = l_r[reg] * alpha + ls;
      #pragma unroll
      for (int f = 0; f < 4; ++f) acc[f][reg] *= alpha;
      unsigned short* prp = plw + (quad * 4 + reg) * PADK + nl;
      prp[0] = us[0]; prp[16] = us[1]; prp[32] = us[2]; prp[48] = us[3];
    }
    bf16x8 pA0 = *(const bf16x8*)(plw + nl * PADK + quad * 8);
    bf16x8 pA1 = *(const bf16x8*)(plw + nl * PADK + 32 + quad * 8);
    #pragma unroll
    for (int f = 0; f < 4; ++f) {
      const unsigned short* vr = vT + (f * 16 + nl) * PADK;
      bf16x8 v0 = *(const bf16x8*)(vr + quad * 8);
      bf16x8 v1 = *(const bf16x8*)(vr + 32 + quad * 8);
      acc[f] = __builtin_amdgcn_mfma_f32_16x16x32_bf16(pA0, v0, acc[f], 0, 0, 0);
      acc[f] = __builtin_amdgcn_mfma_f32_16x16x32_bf16(pA1, v1, acc[f], 0, 0, 0);
    }
    __syncthreads();
  }

  float* orow = obuf + ((size_t)(bh * Nn + i0 + w * 16)) * Dd;
  #pragma unroll
  for (int f = 0; f < 4; ++f)
    #pragma unroll
    for (int reg = 0; reg < 4; ++reg)
      orow[(quad * 4 + reg) * Dd + f * 16 + nl] = acc[f][reg] / l_r[reg];
}

// ---------------------------------------------------------------------------
// Scatter gated o into dense bf16 xeg[T][KR]
// ---------------------------------------------------------------------------
__global__ __launch_bounds__(256) void scatter_kernel(
    const float* __restrict__ obuf, const int* __restrict__ idx,
    const float* __restrict__ gate, unsigned short* __restrict__ xeg)
{
  const int t = blockIdx.x, b = t >> 11, nn = t & (Nn - 1);
  for (int i = threadIdx.x; i < Hh * Dd; i += 256) {
    int h = i >> 6, d = i & 63;
    int e = idx[t * Hh + h];
    float g = gate[t * Hh + h];
    xeg[(size_t)t * KR + e * Dd + d] =
        f2bf(g * obuf[((size_t)(b * Hh + h) * Nn + nn) * Dd + d]);
  }
  if (threadIdx.x < Hh) {
    int e = idx[t * Hh + threadIdx.x];
    xeg[(size_t)t * KR + 1536 + e] = f2bf(gate[t * Hh + threadIdx.x]);
  }
}

// ---------------------------------------------------------------------------
// Aux loss: reduce bstats[49][NB2] then finalize (deterministic, no atomics)
// ---------------------------------------------------------------------------
__global__ __launch_bounds__(256) void aux_kernel(
    const float* __restrict__ bstats, float* __restrict__ out, int out_size)
{
  __shared__ float red[49];
  const int tid = threadIdx.x, w = tid >> 6, lane = tid & 63;
  for (int j = w; j < 49; j += 4) {
    const float* row = bstats + (size_t)j * NB2;
    float s = 0.f;
    for (int i = lane; i < NB2; i += 64) s += row[i];
    for (int o = 32; o; o >>= 1) s += __shfl_xor(s, o);
    if (lane == 0) red[j] = s;
  }
  __syncthreads();
  if (tid == 0) {
    float pt = 0.f, ft = 0.f, sw = 0.f;
    for (int e = 0; e < Ee; ++e) { pt += red[e]; ft += red[24 + e]; }
    for (int e = 0; e < Ee; ++e) sw += red[e] * red[24 + e];
    float sswitch = (float)Ee * sw / (pt * ft);
    float z = red[48] * (1.0f / (float)T_);
    out[out_size - 1] = 0.1f * sswitch + 0.001f * z;
  }
}

// ---------------------------------------------------------------------------
extern "C" void kernel_launch(void* const* d_in, const int* in_sizes, int n_in,
                              void* d_out, int out_size, void* d_ws, size_t ws_size,
                              hipStream_t stream)
{
  const float* x     = (const float*)d_in[0];
  const float* wg    = (const float*)d_in[1];
  const float* W_in  = (const float*)d_in[2];
  const float* b_in  = (const float*)d_in[3];
  const float* W_out = (const float*)d_in[4];
  const float* b_out = (const float*)d_in[5];
  const float* W_kv  = (const float*)d_in[6];
  const float* b_kv  = (const float*)d_in[7];
  float* out = (float*)d_out;

  char* ws = (char*)d_ws;
  size_t off = 0;
  auto carve = [&](size_t bytes) -> void* {
    void* p = ws + off;
    off = (off + bytes + 255) & ~(size_t)255;
    return p;
  };
  int*            idx    = (int*)           carve((size_t)T_ * Hh * 4);
  float*          gate   = (float*)         carve((size_t)T_ * Hh * 4);
  float*          bstats = (float*)         carve((size_t)49 * NB2 * 4);
  float*          lpart  = (float*)         carve((size_t)T_ * KS * Ee * 4);
  unsigned short* xb     = (unsigned short*)carve((size_t)T_ * Cc * 2);
  unsigned short* BqT    = (unsigned short*)carve((size_t)Ee * Dd * Cc * 2);
  unsigned short* BrT    = (unsigned short*)carve((size_t)Cc * KR * 2);
  unsigned short* BkvT   = (unsigned short*)carve((size_t)128 * Cc * 2);
  unsigned short* kbuf   = (unsigned short*)carve((size_t)T_ * Dd * 2);
  unsigned short* vtbuf  = (unsigned short*)carve((size_t)T_ * Dd * 2);
  unsigned short* qallb  = (unsigned short*)carve((size_t)T_ * Ee * Dd * 2);
  unsigned short* qh     = (unsigned short*)carve((size_t)T_ * Hh * Dd * 2);
  float*          obuf   = (float*)         carve((size_t)T_ * Hh * Dd * 4);
  unsigned short* xeg    = (unsigned short*)carve((size_t)T_ * KR * 2);

  hipMemsetAsync(xeg, 0, (size_t)T_ * KR * 2, stream);

  // conversions
  convert_x_kernel  <<<T_ * Cc / 4 / 256, 256, 0, stream>>>(x, xb);
  convert_win_kernel<<<dim3(Ee, Cc / 64), 256, 0, stream>>>(W_in, BqT);
  convert_wout_kernel<<<dim3(KR / 32, Cc / 64), 256, 0, stream>>>(W_out, b_out, BrT);
  convert_wkv_kernel<<<Cc / 64, 256, 0, stream>>>(W_kv, BkvT);

  // gating
  gate1_kernel<<<dim3(T_ / 256, KS), 256, 0, stream>>>(x, wg, lpart);
  gate2_kernel<<<NB2, 256, 0, stream>>>(lpart, idx, gate, bstats);

  // kv: K -> kbuf [B][N][D], V -> vtbuf [B][D][N]
  gemm_bt_kernel<2><<<dim3(T_ / 128, 1), 256, 0, stream>>>(
      xb, BkvT, b_kv, kbuf, vtbuf, Cc, 128);
  // q_all = xb @ BqT^T + b_in -> bf16 [T][1536]
  gemm_bt_kernel<1><<<dim3(T_ / 128, Ee * Dd / 128), 256, 0, stream>>>(
      xb, BqT, b_in, qallb, nullptr, Cc, Ee * Dd);

  gatherq_kernel<<<T_, 256, 0, stream>>>(qallb, idx, qh);
  attn_kernel<<<dim3(Nn / 64, Bb * Hh), 256, 0, stream>>>(qh, kbuf, vtbuf, obuf);
  scatter_kernel<<<T_, 256, 0, stream>>>(obuf, idx, gate, xeg);

  // out = xeg @ BrT^T -> f32 [T][768]
  gemm_bt_kernel<0><<<dim3(T_ / 128, Cc / 128), 256, 0, stream>>>(
      xeg, BrT, nullptr, out, nullptr, KR, Cc);

  aux_kernel<<<1, 256, 0, stream>>>(bstats, out, out_size);
}